// Round 8
// baseline (453.267 us; speedup 1.0000x reference)
//
#include <hip/hip_runtime.h>
#include <hip/hip_bf16.h>

// Problem dims (fixed by reference): B=16, D=512, N=2048, h=8, Nh=256.
#define DD  512
#define NN  2048
#define BB  16
#define NHD 256

typedef unsigned short u16;
typedef __attribute__((ext_vector_type(4))) float f32x4;
typedef __attribute__((ext_vector_type(8))) short s16x8;
typedef __attribute__((ext_vector_type(4))) u16   u16x4;

static __device__ __forceinline__ u16 f2bf(float f) {
  __hip_bfloat16 h = __float2bfloat16(f);
  return *reinterpret_cast<u16*>(&h);
}
static __device__ __forceinline__ float bf2f(u16 u) {
  union { unsigned int i; float f; } v; v.i = ((unsigned int)u) << 16; return v.f;
}
static __device__ __forceinline__ f32x4 mfma_bf16(s16x8 a, s16x8 b, f32x4 c) {
  return __builtin_amdgcn_mfma_f32_16x16x32_bf16(a, b, c, 0, 0, 0);
}
static __device__ __forceinline__ void gload_lds16(const u16* g, u16* l) {
  __builtin_amdgcn_global_load_lds(
      (const __attribute__((address_space(1))) unsigned int*)g,
      (__attribute__((address_space(3))) unsigned int*)l, 16, 0, 0);
}
// raw barrier + compile-time pin (rule 18: sched_barrier after asm waitcnt)
static __device__ __forceinline__ void barrier_raw() {
  __builtin_amdgcn_sched_barrier(0);
  __builtin_amdgcn_s_barrier();
  __builtin_amdgcn_sched_barrier(0);
}
#define WAITCNT(s) do { asm volatile("s_waitcnt " s ::: "memory"); \
                        __builtin_amdgcn_sched_barrier(0); } while (0)

// ---------------------------------------------------------------- weights f32 -> bf16
__global__ __launch_bounds__(256) void k_cvt_w(const float* __restrict__ w0,
                                               const float* __restrict__ w1,
                                               const float* __restrict__ w2,
                                               const float* __restrict__ w3,
                                               u16* __restrict__ out) {
  const float* srcs[4] = {w0, w1, w2, w3};
  const float* s = srcs[blockIdx.y];
  u16* o = out + (size_t)blockIdx.y * (DD * DD);
  int idx = blockIdx.x * 256 + threadIdx.x;
  float4 v = *(const float4*)(s + (size_t)idx * 4);
  u16x4 u = {f2bf(v.x), f2bf(v.y), f2bf(v.z), f2bf(v.w)};
  *(u16x4*)(o + (size_t)idx * 4) = u;
}

// ---------------------------------------------------------------- X (B,D,N) f32 -> XT (B,N,D) bf16
__global__ __launch_bounds__(256) void k_transpose(const float* __restrict__ X,
                                                   u16* __restrict__ XT) {
  __shared__ float t[64][68];
  const int tid = threadIdx.x;
  const int n0 = blockIdx.x * 64, d0 = blockIdx.y * 64, b = blockIdx.z;
  const float* Xb = X + ((size_t)b * DD + d0) * NN + n0;
#pragma unroll
  for (int i = 0; i < 4; ++i) {
    int r = (tid >> 4) + i * 16;
    int c = (tid & 15) * 4;
    float4 v = *(const float4*)(Xb + (size_t)r * NN + c);
    t[r][c] = v.x; t[r][c + 1] = v.y; t[r][c + 2] = v.z; t[r][c + 3] = v.w;
  }
  __syncthreads();
  u16* Ob = XT + ((size_t)b * NN + n0) * DD + d0;
#pragma unroll
  for (int i = 0; i < 4; ++i) {
    int n = (tid >> 4) + i * 16;
    int d = (tid & 15) * 4;
    u16x4 u = {f2bf(t[d][n]), f2bf(t[d + 1][n]), f2bf(t[d + 2][n]), f2bf(t[d + 3][n])};
    *(u16x4*)(Ob + (size_t)n * DD + d) = u;
  }
}

// ================================================================ shared GEMM building blocks
#define GEMM_STAGE(Ag, lda, Bg, ldb, buf, kt)                                   \
  {                                                                             \
    _Pragma("unroll")                                                           \
    for (int j = 0; j < 4; ++j) {                                               \
      int s = j * 256 + w * 64 + lane;                                          \
      int row = s >> 3, u = s & 7;                                              \
      int col = ((u ^ (row & 7)) * 8);                                          \
      gload_lds16(Ag + (size_t)row * lda + (kt) * 64 + col, &Ab[buf][s * 8]);   \
      gload_lds16(Bg + (size_t)row * ldb + (kt) * 64 + col, &Bb[buf][s * 8]);   \
    }                                                                           \
  }

#define GEMM_COMPUTE(buf)                                                       \
  {                                                                             \
    _Pragma("unroll")                                                           \
    for (int ks = 0; ks < 2; ++ks) {                                            \
      s16x8 av[4], bv[4];                                                       \
      _Pragma("unroll")                                                         \
      for (int m = 0; m < 4; ++m) {                                             \
        int row = wm + m * 16 + r;                                              \
        av[m] = *(const s16x8*)&Ab[buf][row * 64 + (((ks * 4 + g) ^ (row & 7)) * 8)]; \
      }                                                                         \
      _Pragma("unroll")                                                         \
      for (int nf = 0; nf < 4; ++nf) {                                          \
        int row = wn + nf * 16 + r;                                             \
        bv[nf] = *(const s16x8*)&Bb[buf][row * 64 + (((ks * 4 + g) ^ (row & 7)) * 8)]; \
      }                                                                         \
      _Pragma("unroll")                                                         \
      for (int m = 0; m < 4; ++m)                                               \
        _Pragma("unroll")                                                       \
        for (int nf = 0; nf < 4; ++nf)                                          \
          acc[m][nf] = mfma_bf16(av[m], bv[nf], acc[m][nf]);                    \
    }                                                                           \
  }

#define GEMM_PREAMBLE                                                           \
  __shared__ __align__(16) u16 Ab[2][128 * 64];                                 \
  __shared__ __align__(16) u16 Bb[2][128 * 64];                                 \
  const int tid = threadIdx.x;                                                  \
  const int lane = tid & 63, w = tid >> 6;                                      \
  const int wm = (w >> 1) * 64, wn = (w & 1) * 64;                              \
  const int r = lane & 15, g = lane >> 4;                                       \
  f32x4 acc[4][4] = {};

#define GEMM_MAINLOOP(Ag, lda, Bg, ldb, nkt)                                    \
  GEMM_STAGE(Ag, lda, Bg, ldb, 0, 0);                                           \
  __syncthreads();                                                              \
  for (int kt = 0; kt < (nkt) - 1; ++kt) {                                      \
    GEMM_STAGE(Ag, lda, Bg, ldb, (kt & 1) ^ 1, kt + 1);                         \
    GEMM_COMPUTE(kt & 1);                                                       \
    __syncthreads();                                                            \
  }                                                                             \
  GEMM_COMPUTE(((nkt) - 1) & 1);

// ---------------------------------------------------------------- generic NT GEMM (projections)
template <typename OUT_T>
__global__ __launch_bounds__(256) void k_gemm_nt(
    const u16* __restrict__ A, long long a_bs, int lda,
    const u16* __restrict__ B, long long b_bs, int ldb,
    OUT_T* __restrict__ C, long long c_bs, int ldc, int K) {
  GEMM_PREAMBLE
  const int m0 = blockIdx.x * 128, n0 = blockIdx.y * 128;
  const u16* Ag = A + (size_t)blockIdx.z * a_bs + (size_t)m0 * lda;
  const u16* Bg = B + (size_t)blockIdx.z * b_bs + (size_t)n0 * ldb;
  const int nkt = K >> 6;
  GEMM_MAINLOOP(Ag, lda, Bg, ldb, nkt);

  OUT_T* Cg = C + (size_t)blockIdx.z * c_bs;
#pragma unroll
  for (int m = 0; m < 4; ++m)
#pragma unroll
    for (int nf = 0; nf < 4; ++nf)
#pragma unroll
      for (int j = 0; j < 4; ++j) {
        int row = m0 + wm + m * 16 + g * 4 + j;
        int col = n0 + wn + nf * 16 + r;
        float v = acc[m][nf][j];
        if constexpr (sizeof(OUT_T) == 2) Cg[(size_t)row * ldc + col] = f2bf(v);
        else                              Cg[(size_t)row * ldc + col] = v;
      }
}

// ---------------------------------------------------------------- fused attention (v5)
// Geometry = v4 (block = (b,h,d-tile 64), 512 thr, 52 KB LDS -> 3 blocks/CU).
// RACE-FIXED schedule vs v4:
//  * all stage issues moved AFTER the substep barrier (every wave's previous-phase
//    LDS reads are drained by its own lgkmcnt(0) before that barrier -> no W-A-R).
//  * V prefetch distance +1 (issue V(s+1) at substep s): slot-sharing V(t)/V(t+3)
//    are separated by the end-of-et barrier (v4's +2 clobbered V(2et) pre-PV).
// Per-wave vmcnt ledger (issue order per substep: V(s+1) then K(s+2)):
//  prologue leaves [K0 V0 K1]; steady: cn0 vmcnt(2), cn1 vmcnt(2), PV vmcnt(3);
//  et=15 tail: cn0 vmcnt(2), cn1 vmcnt(1), PV vmcnt(0).
__global__ __launch_bounds__(512, 6) void k_attn_fused(
    const u16* __restrict__ Qdn, const u16* __restrict__ Kdn,
    const u16* __restrict__ VT,  const u16* __restrict__ XqT,
    u16* __restrict__ And) {
  __shared__ __align__(16) u16 L[26624];   // 52 KB: Kr 3x4096 | Vr 3x4096 | Ps 2048
  u16* Kr = L;
  u16* Vr = L + 12288;
  char* Psb = (char*)(L + 24576);          // Ps: 64 rows x 64 B

  const int tid = threadIdx.x;
  const int lane = tid & 63, w = tid >> 6;
  const int r = lane & 15, g = lane >> 4;
  const int dq = w >> 1, eh = w & 1;       // QK: wave = (16 d-rows) x (16 e-cols)
  const int nq = w >> 1, dh = w & 1;       // PV: wave = (32 npos/slice) x (32 d-cols)
  const int bid = blockIdx.x;
  const int dt = bid >> 7, hb = bid & 127; // 8 d-tiles of one (b,h) share bid%8 (XCD)
  const int h = hb & 7, b = hb >> 3;
  const int d0 = dt * 64, hn0 = h * NHD;

  const u16* Qg = Qdn + ((size_t)b * DD + d0) * NN + hn0;
  const u16* Kg = Kdn + ((size_t)b * DD) * NN + hn0;
  const u16* Vg = VT + ((size_t)b * NN + hn0) * DD;

  auto stage_k = [&](int s) {              // K[(s>>1)*32 +32e][(s&1)*128 +128n] -> Kr[s%3]
    const int e0 = (s >> 1) * 32, n0 = (s & 1) * 128;
    u16* dst = Kr + (s % 3) * 4096;
    int row = tid >> 4, u = tid & 15;      // 512 slots of 16B; 16 chunks/row
    gload_lds16(Kg + (size_t)(e0 + row) * NN + n0 + ((u ^ (row & 7)) * 8), dst + tid * 8);
  };
  auto stage_v = [&](int t) {              // V slice t: rows {x*64+(t&1)*32+i} x 32e -> Vr[t%3]
    const int e0 = (t >> 1) * 32, j = t & 1;
    u16* dst = Vr + (t % 3) * 4096;
    int rl = tid >> 2, u = tid & 3;        // 512 slots; 4 chunks/row (64B rows)
    int gn = (rl >> 5) * 64 + j * 32 + (rl & 31);
    gload_lds16(Vg + (size_t)gn * DD + e0 + ((u ^ (rl & 3)) * 8), dst + tid * 8);
  };

  // ---- prologue: Q[64][256] staged through Kr/Vr region -> qf regs, then K0,V0,K1
#pragma unroll
  for (int jj = 0; jj < 4; ++jj) {
    int s = jj * 512 + tid;                // 2048 slots; 32 chunks/row (512B rows)
    int row = s >> 5, u = s & 31;
    gload_lds16(Qg + (size_t)row * NN + ((u ^ (row & 7)) * 8), L + s * 8);
  }
  WAITCNT("vmcnt(0)");
  barrier_raw();
  s16x8 qf[8];                             // 32 VGPR: wave's 16 d-rows x 256 n
  {
    const int qrow = dq * 16 + r;
#pragma unroll
    for (int k2 = 0; k2 < 8; ++k2)
      qf[k2] = *(const s16x8*)&L[qrow * 256 + (((k2 * 4 + g) ^ (qrow & 7)) * 8)];
  }
  WAITCNT("lgkmcnt(0)");
  barrier_raw();                           // Q region free; issues below can't race
  stage_k(0); stage_v(0); stage_k(1);      // outstanding: [K0 V0 K1]

  float psum[4] = {};
  f32x4 acc_o[2][2][2] = {};               // [slice j][ms][nf-d]

  for (int et = 0; et < 16; ++et) {
    f32x4 acc_s = {};
    // ---- QK^T: 2 substeps over n (128 each)
#pragma unroll
    for (int cn = 0; cn < 2; ++cn) {
      const int s = et * 2 + cn;
      if (cn == 0)      WAITCNT("vmcnt(2)");   // K(s) landed (ledger)
      else if (et < 15) WAITCNT("vmcnt(2)");
      else              WAITCNT("vmcnt(1)");
      barrier_raw();                       // K chunk ready; all prev reads drained
      // stage AFTER the barrier: no W-A-R race with other waves' reads
      if (s + 1 < 32) stage_v(s + 1);
      if (s + 2 < 32) stage_k(s + 2);
      const u16* kb = Kr + (s % 3) * 4096;
      const int rowe = eh * 16 + r;
      __builtin_amdgcn_s_setprio(1);
#pragma unroll
      for (int kq = 0; kq < 4; ++kq) {
        s16x8 bv = *(const s16x8*)&kb[rowe * 128 + (((kq * 4 + g) ^ (rowe & 7)) * 8)];
        acc_s = mfma_bf16(qf[cn * 4 + kq], bv, acc_s);
      }
      __builtin_amdgcn_s_setprio(0);
      WAITCNT("lgkmcnt(0)");               // K reads drained (license next writes)
    }
    // ---- exp -> Ps, rowsum partials in regs
#pragma unroll
    for (int j = 0; j < 4; ++j) {
      int rowd = dq * 16 + g * 4 + j;
      int cole = eh * 16 + r;
      float p = __expf(acc_s[j] * 0.0625f);   // scale 1/sqrt(Nh)=1/16
      psum[j] += p;
      *(u16*)(Psb + rowd * 64 + (((cole * 2) ^ ((rowd & 3) << 4)))) = f2bf(p);
    }
    WAITCNT("lgkmcnt(0)");                 // Ps writes drained
    if (et < 15) WAITCNT("vmcnt(3)");      // V(2et),V(2et+1) landed
    else         WAITCNT("vmcnt(0)");
    barrier_raw();                         // Ps + both V slices ready
    // ---- PV: 2 slice phases
#pragma unroll
    for (int j = 0; j < 2; ++j) {
      const u16* vb = Vr + ((et * 2 + j) % 3) * 4096;
      s16x8 pb[2];
#pragma unroll
      for (int nf = 0; nf < 2; ++nf) {
        int rowd = dh * 32 + nf * 16 + r;
        pb[nf] = *(const s16x8*)(Psb + rowd * 64 + ((g * 16) ^ ((rowd & 3) << 4)));
      }
      __builtin_amdgcn_s_setprio(1);
#pragma unroll
      for (int ms = 0; ms < 2; ++ms) {
        int rl = nq * 32 + ms * 16 + r;
        s16x8 av = *(const s16x8*)((const char*)vb + rl * 64 + ((g * 16) ^ ((rl & 3) << 4)));
        acc_o[j][ms][0] = mfma_bf16(av, pb[0], acc_o[j][ms][0]);
        acc_o[j][ms][1] = mfma_bf16(av, pb[1], acc_o[j][ms][1]);
      }
      __builtin_amdgcn_s_setprio(0);
    }
    WAITCNT("lgkmcnt(0)");
    barrier_raw();                         // PV reads drained before next-et issues
  }

  // ---- rowsum reduce (deterministic; overlays dead Kr region)
  float* rs = (float*)L;                   // [8][16] partials, then [64] inv at +128
#pragma unroll
  for (int j = 0; j < 4; ++j) {
    float v = psum[j];
    v += __shfl_xor(v, 1);
    v += __shfl_xor(v, 2);
    v += __shfl_xor(v, 4);
    v += __shfl_xor(v, 8);
    if (r == 0) rs[w * 16 + g * 4 + j] = v;
  }
  __syncthreads();
  if (tid < 64) {
    int dqi = tid >> 4, i = tid & 15;
    rs[128 + tid] = 1.0f / (rs[(dqi * 2) * 16 + i] + rs[(dqi * 2 + 1) * 16 + i]);
  }
  __syncthreads();

  const u16* Xg = XqT + ((size_t)b * NN + hn0) * DD + d0;
  u16* Ag = And + ((size_t)b * NN + hn0) * DD + d0;
#pragma unroll
  for (int j = 0; j < 2; ++j)
#pragma unroll
    for (int ms = 0; ms < 2; ++ms)
#pragma unroll
      for (int nf = 0; nf < 2; ++nf) {
        const int dc = dh * 32 + nf * 16 + r;
        const float inv = rs[128 + dc];
#pragma unroll
        for (int jj = 0; jj < 4; ++jj) {
          const int npos = nq * 64 + j * 32 + ms * 16 + g * 4 + jj;
          float o = acc_o[j][ms][nf][jj] * inv;
          float xq = bf2f(Xg[(size_t)npos * DD + dc]);
          Ag[(size_t)npos * DD + dc] = f2bf(xq - o);
        }
      }
}

// ----------------------------------------------------------------
extern "C" void kernel_launch(void* const* d_in, const int* in_sizes, int n_in,
                              void* d_out, int out_size, void* d_ws, size_t ws_size,
                              hipStream_t stream) {
  const float* Xq = (const float*)d_in[0];
  const float* Xk = (const float*)d_in[1];
  const float* Xv = (const float*)d_in[2];
  const float* Wq = (const float*)d_in[3];
  const float* Wk = (const float*)d_in[4];
  const float* Wv = (const float*)d_in[5];
  const float* Wo = (const float*)d_in[6];
  float* out = (float*)d_out;

  char* ws = (char*)d_ws;
  const size_t MB = 1024 * 1024;
  // ws (98 MB): Wb [0,2) | XqT [2,34) | Z2 [34,66): XvT -> XkT -> And | Z3 [66,98): Qdn
  // d_out (64+ MB): VTb [0,32) + Kdn [32,64) as scratch, overwritten by final GEMM.
  u16* Wb  = (u16*)ws;
  u16* XqT = (u16*)(ws + 2 * MB);
  u16* Z2  = (u16*)(ws + 34 * MB);
  u16* And = Z2;                                  // after XkT is dead
  u16* Qdn = (u16*)(ws + 66 * MB);
  u16* VTb = (u16*)d_out;
  u16* Kdn = (u16*)d_out + (size_t)BB * NN * DD;

  k_cvt_w<<<dim3(256, 4), 256, 0, stream>>>(Wq, Wk, Wv, Wo, Wb);

  // V path first so Z2 frees for XkT
  k_transpose<<<dim3(NN / 64, DD / 64, BB), 256, 0, stream>>>(Xv, Z2);  // XvT
  k_gemm_nt<u16><<<dim3(NN / 128, DD / 128, BB), 256, 0, stream>>>(
      Z2, (long long)NN * DD, DD,
      Wb + 2 * DD * DD, 0, DD,
      VTb, (long long)NN * DD, DD, DD);

  k_transpose<<<dim3(NN / 64, DD / 64, BB), 256, 0, stream>>>(Xq, XqT);
  k_gemm_nt<u16><<<dim3(DD / 128, NN / 128, BB), 256, 0, stream>>>(
      Wb, 0, DD,
      XqT, (long long)NN * DD, DD,
      Qdn, (long long)DD * NN, NN, DD);

  k_transpose<<<dim3(NN / 64, DD / 64, BB), 256, 0, stream>>>(Xk, Z2);  // XkT
  k_gemm_nt<u16><<<dim3(DD / 128, NN / 128, BB), 256, 0, stream>>>(
      Wb + 1 * DD * DD, 0, DD,
      Z2, (long long)NN * DD, DD,
      Kdn, (long long)DD * NN, NN, DD);

  // fused scores/softmax/PV/residual -> And (overlays dead XkT)
  k_attn_fused<<<dim3(1024), 512, 0, stream>>>(Qdn, Kdn, VTb, XqT, And);

  // out[b][o][n] = sum_i Wo[o][i] * And[b][n][i]  (fp32; overwrites VTb/Kdn scratch)
  k_gemm_nt<float><<<dim3(DD / 128, NN / 128, BB), 256, 0, stream>>>(
      Wb + 3 * DD * DD, 0, DD,
      And, (long long)NN * DD, DD,
      out, (long long)DD * NN, NN, DD);
}

// Round 9
// 251.193 us; speedup vs baseline: 1.8045x; 1.8045x over previous
//
#include <hip/hip_runtime.h>
#include <hip/hip_bf16.h>

// Problem dims (fixed by reference): B=16, D=512, N=2048, h=8, Nh=256.
#define DD  512
#define NN  2048
#define BB  16
#define NHD 256

typedef unsigned short u16;
typedef __attribute__((ext_vector_type(4))) float f32x4;
typedef __attribute__((ext_vector_type(8))) short s16x8;
typedef __attribute__((ext_vector_type(4))) u16   u16x4;

static __device__ __forceinline__ u16 f2bf(float f) {
  __hip_bfloat16 h = __float2bfloat16(f);
  return *reinterpret_cast<u16*>(&h);
}
static __device__ __forceinline__ float bf2f(u16 u) {
  union { unsigned int i; float f; } v; v.i = ((unsigned int)u) << 16; return v.f;
}
static __device__ __forceinline__ f32x4 mfma_bf16(s16x8 a, s16x8 b, f32x4 c) {
  return __builtin_amdgcn_mfma_f32_16x16x32_bf16(a, b, c, 0, 0, 0);
}
static __device__ __forceinline__ void gload_lds16(const u16* g, u16* l) {
  __builtin_amdgcn_global_load_lds(
      (const __attribute__((address_space(1))) unsigned int*)g,
      (__attribute__((address_space(3))) unsigned int*)l, 16, 0, 0);
}
// raw barrier + compile-time pin (rule 18: sched_barrier after asm waitcnt)
static __device__ __forceinline__ void barrier_raw() {
  __builtin_amdgcn_sched_barrier(0);
  __builtin_amdgcn_s_barrier();
  __builtin_amdgcn_sched_barrier(0);
}
#define WAITCNT(s) do { asm volatile("s_waitcnt " s ::: "memory"); \
                        __builtin_amdgcn_sched_barrier(0); } while (0)

// ---------------------------------------------------------------- weights f32 -> bf16
__global__ __launch_bounds__(256) void k_cvt_w(const float* __restrict__ w0,
                                               const float* __restrict__ w1,
                                               const float* __restrict__ w2,
                                               const float* __restrict__ w3,
                                               u16* __restrict__ out) {
  const float* srcs[4] = {w0, w1, w2, w3};
  const float* s = srcs[blockIdx.y];
  u16* o = out + (size_t)blockIdx.y * (DD * DD);
  int idx = blockIdx.x * 256 + threadIdx.x;
  float4 v = *(const float4*)(s + (size_t)idx * 4);
  u16x4 u = {f2bf(v.x), f2bf(v.y), f2bf(v.z), f2bf(v.w)};
  *(u16x4*)(o + (size_t)idx * 4) = u;
}

// ---------------------------------------------------------------- X (B,D,N) f32 -> XT (B,N,D) bf16
__global__ __launch_bounds__(256) void k_transpose(const float* __restrict__ X,
                                                   u16* __restrict__ XT) {
  __shared__ float t[64][68];
  const int tid = threadIdx.x;
  const int n0 = blockIdx.x * 64, d0 = blockIdx.y * 64, b = blockIdx.z;
  const float* Xb = X + ((size_t)b * DD + d0) * NN + n0;
#pragma unroll
  for (int i = 0; i < 4; ++i) {
    int r = (tid >> 4) + i * 16;
    int c = (tid & 15) * 4;
    float4 v = *(const float4*)(Xb + (size_t)r * NN + c);
    t[r][c] = v.x; t[r][c + 1] = v.y; t[r][c + 2] = v.z; t[r][c + 3] = v.w;
  }
  __syncthreads();
  u16* Ob = XT + ((size_t)b * NN + n0) * DD + d0;
#pragma unroll
  for (int i = 0; i < 4; ++i) {
    int n = (tid >> 4) + i * 16;
    int d = (tid & 15) * 4;
    u16x4 u = {f2bf(t[d][n]), f2bf(t[d + 1][n]), f2bf(t[d + 2][n]), f2bf(t[d + 3][n])};
    *(u16x4*)(Ob + (size_t)n * DD + d) = u;
  }
}

// ================================================================ shared GEMM building blocks
#define GEMM_STAGE(Ag, lda, Bg, ldb, buf, kt)                                   \
  {                                                                             \
    _Pragma("unroll")                                                           \
    for (int j = 0; j < 4; ++j) {                                               \
      int s = j * 256 + w * 64 + lane;                                          \
      int row = s >> 3, u = s & 7;                                              \
      int col = ((u ^ (row & 7)) * 8);                                          \
      gload_lds16(Ag + (size_t)row * lda + (kt) * 64 + col, &Ab[buf][s * 8]);   \
      gload_lds16(Bg + (size_t)row * ldb + (kt) * 64 + col, &Bb[buf][s * 8]);   \
    }                                                                           \
  }

#define GEMM_COMPUTE(buf)                                                       \
  {                                                                             \
    _Pragma("unroll")                                                           \
    for (int ks = 0; ks < 2; ++ks) {                                            \
      s16x8 av[4], bv[4];                                                       \
      _Pragma("unroll")                                                         \
      for (int m = 0; m < 4; ++m) {                                             \
        int row = wm + m * 16 + r;                                              \
        av[m] = *(const s16x8*)&Ab[buf][row * 64 + (((ks * 4 + g) ^ (row & 7)) * 8)]; \
      }                                                                         \
      _Pragma("unroll")                                                         \
      for (int nf = 0; nf < 4; ++nf) {                                          \
        int row = wn + nf * 16 + r;                                             \
        bv[nf] = *(const s16x8*)&Bb[buf][row * 64 + (((ks * 4 + g) ^ (row & 7)) * 8)]; \
      }                                                                         \
      _Pragma("unroll")                                                         \
      for (int m = 0; m < 4; ++m)                                               \
        _Pragma("unroll")                                                       \
        for (int nf = 0; nf < 4; ++nf)                                          \
          acc[m][nf] = mfma_bf16(av[m], bv[nf], acc[m][nf]);                    \
    }                                                                           \
  }

#define GEMM_PREAMBLE                                                           \
  __shared__ __align__(16) u16 Ab[2][128 * 64];                                 \
  __shared__ __align__(16) u16 Bb[2][128 * 64];                                 \
  const int tid = threadIdx.x;                                                  \
  const int lane = tid & 63, w = tid >> 6;                                      \
  const int wm = (w >> 1) * 64, wn = (w & 1) * 64;                              \
  const int r = lane & 15, g = lane >> 4;                                       \
  f32x4 acc[4][4] = {};

#define GEMM_MAINLOOP(Ag, lda, Bg, ldb, nkt)                                    \
  GEMM_STAGE(Ag, lda, Bg, ldb, 0, 0);                                           \
  __syncthreads();                                                              \
  for (int kt = 0; kt < (nkt) - 1; ++kt) {                                      \
    GEMM_STAGE(Ag, lda, Bg, ldb, (kt & 1) ^ 1, kt + 1);                         \
    GEMM_COMPUTE(kt & 1);                                                       \
    __syncthreads();                                                            \
  }                                                                             \
  GEMM_COMPUTE(((nkt) - 1) & 1);

// ---------------------------------------------------------------- generic NT GEMM (projections)
template <typename OUT_T>
__global__ __launch_bounds__(256) void k_gemm_nt(
    const u16* __restrict__ A, long long a_bs, int lda,
    const u16* __restrict__ B, long long b_bs, int ldb,
    OUT_T* __restrict__ C, long long c_bs, int ldc, int K) {
  GEMM_PREAMBLE
  const int m0 = blockIdx.x * 128, n0 = blockIdx.y * 128;
  const u16* Ag = A + (size_t)blockIdx.z * a_bs + (size_t)m0 * lda;
  const u16* Bg = B + (size_t)blockIdx.z * b_bs + (size_t)n0 * ldb;
  const int nkt = K >> 6;
  GEMM_MAINLOOP(Ag, lda, Bg, ldb, nkt);

  OUT_T* Cg = C + (size_t)blockIdx.z * c_bs;
#pragma unroll
  for (int m = 0; m < 4; ++m)
#pragma unroll
    for (int nf = 0; nf < 4; ++nf)
#pragma unroll
      for (int j = 0; j < 4; ++j) {
        int row = m0 + wm + m * 16 + g * 4 + j;
        int col = n0 + wn + nf * 16 + r;
        float v = acc[m][nf][j];
        if constexpr (sizeof(OUT_T) == 2) Cg[(size_t)row * ldc + col] = f2bf(v);
        else                              Cg[(size_t)row * ldc + col] = v;
      }
}

// ---------------------------------------------------------------- fused attention (v6)
// = v5 schedule (race-clean, PASSED) with the ONE regression knob reverted:
// __launch_bounds__(512, 4). v5's (512,6) squeezed VGPR to ~85 -> hot-loop spills
// (VGPR_Count 40, WRITE 125MB vs 33MB output, FETCH 580MB, MfmaUtil 5%).
// Natural allocation ~48-64 VGPR -> 64-quantum -> 3 blocks/CU at 52 KB LDS.
// Per-wave vmcnt ledger (issue order per substep: V(s+1) then K(s+2)):
//  prologue leaves [K0 V0 K1]; steady: cn0 vmcnt(2), cn1 vmcnt(2), PV vmcnt(3);
//  et=15 tail: cn0 vmcnt(2), cn1 vmcnt(1), PV vmcnt(0).
__global__ __launch_bounds__(512, 4) void k_attn_fused(
    const u16* __restrict__ Qdn, const u16* __restrict__ Kdn,
    const u16* __restrict__ VT,  const u16* __restrict__ XqT,
    u16* __restrict__ And) {
  __shared__ __align__(16) u16 L[26624];   // 52 KB: Kr 3x4096 | Vr 3x4096 | Ps 2048
  u16* Kr = L;
  u16* Vr = L + 12288;
  char* Psb = (char*)(L + 24576);          // Ps: 64 rows x 64 B

  const int tid = threadIdx.x;
  const int lane = tid & 63, w = tid >> 6;
  const int r = lane & 15, g = lane >> 4;
  const int dq = w >> 1, eh = w & 1;       // QK: wave = (16 d-rows) x (16 e-cols)
  const int nq = w >> 1, dh = w & 1;       // PV: wave = (32 npos/slice) x (32 d-cols)
  const int bid = blockIdx.x;
  const int dt = bid >> 7, hb = bid & 127; // 8 d-tiles of one (b,h) share bid%8 (XCD)
  const int h = hb & 7, b = hb >> 3;
  const int d0 = dt * 64, hn0 = h * NHD;

  const u16* Qg = Qdn + ((size_t)b * DD + d0) * NN + hn0;
  const u16* Kg = Kdn + ((size_t)b * DD) * NN + hn0;
  const u16* Vg = VT + ((size_t)b * NN + hn0) * DD;

  auto stage_k = [&](int s) {              // K[(s>>1)*32 +32e][(s&1)*128 +128n] -> Kr[s%3]
    const int e0 = (s >> 1) * 32, n0 = (s & 1) * 128;
    u16* dst = Kr + (s % 3) * 4096;
    int row = tid >> 4, u = tid & 15;      // 512 slots of 16B; 16 chunks/row
    gload_lds16(Kg + (size_t)(e0 + row) * NN + n0 + ((u ^ (row & 7)) * 8), dst + tid * 8);
  };
  auto stage_v = [&](int t) {              // V slice t: rows {x*64+(t&1)*32+i} x 32e -> Vr[t%3]
    const int e0 = (t >> 1) * 32, j = t & 1;
    u16* dst = Vr + (t % 3) * 4096;
    int rl = tid >> 2, u = tid & 3;        // 512 slots; 4 chunks/row (64B rows)
    int gn = (rl >> 5) * 64 + j * 32 + (rl & 31);
    gload_lds16(Vg + (size_t)gn * DD + e0 + ((u ^ (rl & 3)) * 8), dst + tid * 8);
  };

  // ---- prologue: Q[64][256] staged through Kr/Vr region -> qf regs, then K0,V0,K1
#pragma unroll
  for (int jj = 0; jj < 4; ++jj) {
    int s = jj * 512 + tid;                // 2048 slots; 32 chunks/row (512B rows)
    int row = s >> 5, u = s & 31;
    gload_lds16(Qg + (size_t)row * NN + ((u ^ (row & 7)) * 8), L + s * 8);
  }
  WAITCNT("vmcnt(0)");
  barrier_raw();
  s16x8 qf[8];                             // 32 VGPR: wave's 16 d-rows x 256 n
  {
    const int qrow = dq * 16 + r;
#pragma unroll
    for (int k2 = 0; k2 < 8; ++k2)
      qf[k2] = *(const s16x8*)&L[qrow * 256 + (((k2 * 4 + g) ^ (qrow & 7)) * 8)];
  }
  WAITCNT("lgkmcnt(0)");
  barrier_raw();                           // Q region free; issues below can't race
  stage_k(0); stage_v(0); stage_k(1);      // outstanding: [K0 V0 K1]

  float psum[4] = {};
  f32x4 acc_o[2][2][2] = {};               // [slice j][ms][nf-d]

  for (int et = 0; et < 16; ++et) {
    f32x4 acc_s = {};
    // ---- QK^T: 2 substeps over n (128 each)
#pragma unroll
    for (int cn = 0; cn < 2; ++cn) {
      const int s = et * 2 + cn;
      if (cn == 0)      WAITCNT("vmcnt(2)");   // K(s) landed (ledger)
      else if (et < 15) WAITCNT("vmcnt(2)");
      else              WAITCNT("vmcnt(1)");
      barrier_raw();                       // K chunk ready; all prev reads drained
      // stage AFTER the barrier: no W-A-R race with other waves' reads
      if (s + 1 < 32) stage_v(s + 1);
      if (s + 2 < 32) stage_k(s + 2);
      const u16* kb = Kr + (s % 3) * 4096;
      const int rowe = eh * 16 + r;
      __builtin_amdgcn_s_setprio(1);
#pragma unroll
      for (int kq = 0; kq < 4; ++kq) {
        s16x8 bv = *(const s16x8*)&kb[rowe * 128 + (((kq * 4 + g) ^ (rowe & 7)) * 8)];
        acc_s = mfma_bf16(qf[cn * 4 + kq], bv, acc_s);
      }
      __builtin_amdgcn_s_setprio(0);
      WAITCNT("lgkmcnt(0)");               // K reads drained (license next writes)
    }
    // ---- exp -> Ps, rowsum partials in regs
#pragma unroll
    for (int j = 0; j < 4; ++j) {
      int rowd = dq * 16 + g * 4 + j;
      int cole = eh * 16 + r;
      float p = __expf(acc_s[j] * 0.0625f);   // scale 1/sqrt(Nh)=1/16
      psum[j] += p;
      *(u16*)(Psb + rowd * 64 + (((cole * 2) ^ ((rowd & 3) << 4)))) = f2bf(p);
    }
    WAITCNT("lgkmcnt(0)");                 // Ps writes drained
    if (et < 15) WAITCNT("vmcnt(3)");      // V(2et),V(2et+1) landed
    else         WAITCNT("vmcnt(0)");
    barrier_raw();                         // Ps + both V slices ready
    // ---- PV: 2 slice phases
#pragma unroll
    for (int j = 0; j < 2; ++j) {
      const u16* vb = Vr + ((et * 2 + j) % 3) * 4096;
      s16x8 pb[2];
#pragma unroll
      for (int nf = 0; nf < 2; ++nf) {
        int rowd = dh * 32 + nf * 16 + r;
        pb[nf] = *(const s16x8*)(Psb + rowd * 64 + ((g * 16) ^ ((rowd & 3) << 4)));
      }
      __builtin_amdgcn_s_setprio(1);
#pragma unroll
      for (int ms = 0; ms < 2; ++ms) {
        int rl = nq * 32 + ms * 16 + r;
        s16x8 av = *(const s16x8*)((const char*)vb + rl * 64 + ((g * 16) ^ ((rl & 3) << 4)));
        acc_o[j][ms][0] = mfma_bf16(av, pb[0], acc_o[j][ms][0]);
        acc_o[j][ms][1] = mfma_bf16(av, pb[1], acc_o[j][ms][1]);
      }
      __builtin_amdgcn_s_setprio(0);
    }
    WAITCNT("lgkmcnt(0)");
    barrier_raw();                         // PV reads drained before next-et issues
  }

  // ---- rowsum reduce (deterministic; overlays dead Kr region)
  float* rs = (float*)L;                   // [8][16] partials, then [64] inv at +128
#pragma unroll
  for (int j = 0; j < 4; ++j) {
    float v = psum[j];
    v += __shfl_xor(v, 1);
    v += __shfl_xor(v, 2);
    v += __shfl_xor(v, 4);
    v += __shfl_xor(v, 8);
    if (r == 0) rs[w * 16 + g * 4 + j] = v;
  }
  __syncthreads();
  if (tid < 64) {
    int dqi = tid >> 4, i = tid & 15;
    rs[128 + tid] = 1.0f / (rs[(dqi * 2) * 16 + i] + rs[(dqi * 2 + 1) * 16 + i]);
  }
  __syncthreads();

  const u16* Xg = XqT + ((size_t)b * NN + hn0) * DD + d0;
  u16* Ag = And + ((size_t)b * NN + hn0) * DD + d0;
#pragma unroll
  for (int j = 0; j < 2; ++j)
#pragma unroll
    for (int ms = 0; ms < 2; ++ms)
#pragma unroll
      for (int nf = 0; nf < 2; ++nf) {
        const int dc = dh * 32 + nf * 16 + r;
        const float inv = rs[128 + dc];
#pragma unroll
        for (int jj = 0; jj < 4; ++jj) {
          const int npos = nq * 64 + j * 32 + ms * 16 + g * 4 + jj;
          float o = acc_o[j][ms][nf][jj] * inv;
          float xq = bf2f(Xg[(size_t)npos * DD + dc]);
          Ag[(size_t)npos * DD + dc] = f2bf(xq - o);
        }
      }
}

// ----------------------------------------------------------------
extern "C" void kernel_launch(void* const* d_in, const int* in_sizes, int n_in,
                              void* d_out, int out_size, void* d_ws, size_t ws_size,
                              hipStream_t stream) {
  const float* Xq = (const float*)d_in[0];
  const float* Xk = (const float*)d_in[1];
  const float* Xv = (const float*)d_in[2];
  const float* Wq = (const float*)d_in[3];
  const float* Wk = (const float*)d_in[4];
  const float* Wv = (const float*)d_in[5];
  const float* Wo = (const float*)d_in[6];
  float* out = (float*)d_out;

  char* ws = (char*)d_ws;
  const size_t MB = 1024 * 1024;
  // ws (98 MB): Wb [0,2) | XqT [2,34) | Z2 [34,66): XvT -> XkT -> And | Z3 [66,98): Qdn
  // d_out (64+ MB): VTb [0,32) + Kdn [32,64) as scratch, overwritten by final GEMM.
  u16* Wb  = (u16*)ws;
  u16* XqT = (u16*)(ws + 2 * MB);
  u16* Z2  = (u16*)(ws + 34 * MB);
  u16* And = Z2;                                  // after XkT is dead
  u16* Qdn = (u16*)(ws + 66 * MB);
  u16* VTb = (u16*)d_out;
  u16* Kdn = (u16*)d_out + (size_t)BB * NN * DD;

  k_cvt_w<<<dim3(256, 4), 256, 0, stream>>>(Wq, Wk, Wv, Wo, Wb);

  // V path first so Z2 frees for XkT
  k_transpose<<<dim3(NN / 64, DD / 64, BB), 256, 0, stream>>>(Xv, Z2);  // XvT
  k_gemm_nt<u16><<<dim3(NN / 128, DD / 128, BB), 256, 0, stream>>>(
      Z2, (long long)NN * DD, DD,
      Wb + 2 * DD * DD, 0, DD,
      VTb, (long long)NN * DD, DD, DD);

  k_transpose<<<dim3(NN / 64, DD / 64, BB), 256, 0, stream>>>(Xq, XqT);
  k_gemm_nt<u16><<<dim3(DD / 128, NN / 128, BB), 256, 0, stream>>>(
      Wb, 0, DD,
      XqT, (long long)NN * DD, DD,
      Qdn, (long long)DD * NN, NN, DD);

  k_transpose<<<dim3(NN / 64, DD / 64, BB), 256, 0, stream>>>(Xk, Z2);  // XkT
  k_gemm_nt<u16><<<dim3(DD / 128, NN / 128, BB), 256, 0, stream>>>(
      Wb + 1 * DD * DD, 0, DD,
      Z2, (long long)NN * DD, DD,
      Kdn, (long long)DD * NN, NN, DD);

  // fused scores/softmax/PV/residual -> And (overlays dead XkT)
  k_attn_fused<<<dim3(1024), 512, 0, stream>>>(Qdn, Kdn, VTb, XqT, And);

  // out[b][o][n] = sum_i Wo[o][i] * And[b][n][i]  (fp32; overwrites VTb/Kdn scratch)
  k_gemm_nt<float><<<dim3(DD / 128, NN / 128, BB), 256, 0, stream>>>(
      Wb + 3 * DD * DD, 0, DD,
      And, (long long)NN * DD, DD,
      out, (long long)DD * NN, NN, DD);
}

// Round 10
// 247.370 us; speedup vs baseline: 1.8323x; 1.0155x over previous
//
#include <hip/hip_runtime.h>
#include <hip/hip_bf16.h>

// Problem dims (fixed by reference): B=16, D=512, N=2048, h=8, Nh=256.
#define DD  512
#define NN  2048
#define BB  16
#define NHD 256

typedef unsigned short u16;
typedef __attribute__((ext_vector_type(4))) float f32x4;
typedef __attribute__((ext_vector_type(8))) short s16x8;
typedef __attribute__((ext_vector_type(4))) short s16x4;
typedef __attribute__((ext_vector_type(4))) u16   u16x4;

static __device__ __forceinline__ u16 f2bf(float f) {
  __hip_bfloat16 h = __float2bfloat16(f);
  return *reinterpret_cast<u16*>(&h);
}
static __device__ __forceinline__ float bf2f(u16 u) {
  union { unsigned int i; float f; } v; v.i = ((unsigned int)u) << 16; return v.f;
}
static __device__ __forceinline__ f32x4 mfma_bf16(s16x8 a, s16x8 b, f32x4 c) {
  return __builtin_amdgcn_mfma_f32_16x16x32_bf16(a, b, c, 0, 0, 0);
}
static __device__ __forceinline__ void gload_lds16(const u16* g, u16* l) {
  __builtin_amdgcn_global_load_lds(
      (const __attribute__((address_space(1))) unsigned int*)g,
      (__attribute__((address_space(3))) unsigned int*)l, 16, 0, 0);
}
// raw barrier + compile-time pin (rule 18: sched_barrier after asm waitcnt)
static __device__ __forceinline__ void barrier_raw() {
  __builtin_amdgcn_sched_barrier(0);
  __builtin_amdgcn_s_barrier();
  __builtin_amdgcn_sched_barrier(0);
}
#define WAITCNT(s) do { asm volatile("s_waitcnt " s ::: "memory"); \
                        __builtin_amdgcn_sched_barrier(0); } while (0)

// ---------------------------------------------------------------- weights f32 -> bf16
__global__ __launch_bounds__(256) void k_cvt_w(const float* __restrict__ w0,
                                               const float* __restrict__ w1,
                                               const float* __restrict__ w2,
                                               const float* __restrict__ w3,
                                               u16* __restrict__ out) {
  const float* srcs[4] = {w0, w1, w2, w3};
  const float* s = srcs[blockIdx.y];
  u16* o = out + (size_t)blockIdx.y * (DD * DD);
  int idx = blockIdx.x * 256 + threadIdx.x;
  float4 v = *(const float4*)(s + (size_t)idx * 4);
  u16x4 u = {f2bf(v.x), f2bf(v.y), f2bf(v.z), f2bf(v.w)};
  *(u16x4*)(o + (size_t)idx * 4) = u;
}

// ---------------------------------------------------------------- 3x X (B,D,N) f32 -> XT (B,N,D) bf16
__global__ __launch_bounds__(256) void k_transpose3(const float* __restrict__ x0,
                                                    const float* __restrict__ x1,
                                                    const float* __restrict__ x2,
                                                    u16* __restrict__ o0,
                                                    u16* __restrict__ o1,
                                                    u16* __restrict__ o2) {
  __shared__ float t[64][68];
  const int tid = threadIdx.x;
  const int z = blockIdx.z, which = z >> 4, b = z & 15;
  const float* X = which == 0 ? x0 : (which == 1 ? x1 : x2);
  u16*       XT = which == 0 ? o0 : (which == 1 ? o1 : o2);
  const int n0 = blockIdx.x * 64, d0 = blockIdx.y * 64;
  const float* Xb = X + ((size_t)b * DD + d0) * NN + n0;
#pragma unroll
  for (int i = 0; i < 4; ++i) {
    int r = (tid >> 4) + i * 16;
    int c = (tid & 15) * 4;
    float4 v = *(const float4*)(Xb + (size_t)r * NN + c);
    t[r][c] = v.x; t[r][c + 1] = v.y; t[r][c + 2] = v.z; t[r][c + 3] = v.w;
  }
  __syncthreads();
  u16* Ob = XT + ((size_t)b * NN + n0) * DD + d0;
#pragma unroll
  for (int i = 0; i < 4; ++i) {
    int n = (tid >> 4) + i * 16;
    int d = (tid & 15) * 4;
    u16x4 u = {f2bf(t[d][n]), f2bf(t[d + 1][n]), f2bf(t[d + 2][n]), f2bf(t[d + 3][n])};
    *(u16x4*)(Ob + (size_t)n * DD + d) = u;
  }
}

// ================================================================ shared GEMM building blocks
#define GEMM_STAGE(Ag, lda, Bg, ldb, buf, kt)                                   \
  {                                                                             \
    _Pragma("unroll")                                                           \
    for (int j = 0; j < 4; ++j) {                                               \
      int s = j * 256 + w * 64 + lane;                                          \
      int row = s >> 3, u = s & 7;                                              \
      int col = ((u ^ (row & 7)) * 8);                                          \
      gload_lds16(Ag + (size_t)row * lda + (kt) * 64 + col, &Ab[buf][s * 8]);   \
      gload_lds16(Bg + (size_t)row * ldb + (kt) * 64 + col, &Bb[buf][s * 8]);   \
    }                                                                           \
  }

#define GEMM_COMPUTE(buf)                                                       \
  {                                                                             \
    _Pragma("unroll")                                                           \
    for (int ks = 0; ks < 2; ++ks) {                                            \
      s16x8 av[4], bv[4];                                                       \
      _Pragma("unroll")                                                         \
      for (int m = 0; m < 4; ++m) {                                             \
        int row = wm + m * 16 + r;                                              \
        av[m] = *(const s16x8*)&Ab[buf][row * 64 + (((ks * 4 + g) ^ (row & 7)) * 8)]; \
      }                                                                         \
      _Pragma("unroll")                                                         \
      for (int nf = 0; nf < 4; ++nf) {                                          \
        int row = wn + nf * 16 + r;                                             \
        bv[nf] = *(const s16x8*)&Bb[buf][row * 64 + (((ks * 4 + g) ^ (row & 7)) * 8)]; \
      }                                                                         \
      _Pragma("unroll")                                                         \
      for (int m = 0; m < 4; ++m)                                               \
        _Pragma("unroll")                                                       \
        for (int nf = 0; nf < 4; ++nf)                                          \
          acc[m][nf] = mfma_bf16(av[m], bv[nf], acc[m][nf]);                    \
    }                                                                           \
  }

#define GEMM_PREAMBLE                                                           \
  __shared__ __align__(16) u16 Ab[2][128 * 64];                                 \
  __shared__ __align__(16) u16 Bb[2][128 * 64];                                 \
  const int tid = threadIdx.x;                                                  \
  const int lane = tid & 63, w = tid >> 6;                                      \
  const int wm = (w >> 1) * 64, wn = (w & 1) * 64;                              \
  const int r = lane & 15, g = lane >> 4;                                       \
  f32x4 acc[4][4] = {};

#define GEMM_MAINLOOP(Ag, lda, Bg, ldb, nkt)                                    \
  GEMM_STAGE(Ag, lda, Bg, ldb, 0, 0);                                           \
  __syncthreads();                                                              \
  for (int kt = 0; kt < (nkt) - 1; ++kt) {                                      \
    GEMM_STAGE(Ag, lda, Bg, ldb, (kt & 1) ^ 1, kt + 1);                         \
    GEMM_COMPUTE(kt & 1);                                                       \
    __syncthreads();                                                            \
  }                                                                             \
  GEMM_COMPUTE(((nkt) - 1) & 1);

// ---------------------------------------------------------------- generic NT GEMM (projections)
template <typename OUT_T>
__global__ __launch_bounds__(256) void k_gemm_nt(
    const u16* __restrict__ A, long long a_bs, int lda,
    const u16* __restrict__ B, long long b_bs, int ldb,
    OUT_T* __restrict__ C, long long c_bs, int ldc, int K) {
  GEMM_PREAMBLE
  const int m0 = blockIdx.x * 128, n0 = blockIdx.y * 128;
  const u16* Ag = A + (size_t)blockIdx.z * a_bs + (size_t)m0 * lda;
  const u16* Bg = B + (size_t)blockIdx.z * b_bs + (size_t)n0 * ldb;
  const int nkt = K >> 6;
  GEMM_MAINLOOP(Ag, lda, Bg, ldb, nkt);

  OUT_T* Cg = C + (size_t)blockIdx.z * c_bs;
#pragma unroll
  for (int m = 0; m < 4; ++m)
#pragma unroll
    for (int nf = 0; nf < 4; ++nf)
#pragma unroll
      for (int j = 0; j < 4; ++j) {
        int row = m0 + wm + m * 16 + g * 4 + j;
        int col = n0 + wn + nf * 16 + r;
        float v = acc[m][nf][j];
        if constexpr (sizeof(OUT_T) == 2) Cg[(size_t)row * ldc + col] = f2bf(v);
        else                              Cg[(size_t)row * ldc + col] = v;
      }
}

// ---------------------------------------------------------------- fused attention (v7)
// = v6 (race-clean schedule, 3 blocks/CU) with Ps bank-conflict fix:
//   Ps stride 36 u16 (72B rows, no XOR). Writes: word bank = 8g + r/2 + c ->
//   all 32 banks distinct -> ZERO write conflicts. Reads: two 8B-aligned
//   ds_read_b64 halves (72B rows break 16B alignment), <=4-way uniform.
// LDS 53760B -> 3 blocks/CU (161280 <= 163840).
// Per-wave vmcnt ledger unchanged: prologue leaves [K0 V0 K1];
//  steady: cn0 vmcnt(2), cn1 vmcnt(2), PV vmcnt(3); et=15 tail: 2/1/0.
__global__ __launch_bounds__(512, 4) void k_attn_fused(
    const u16* __restrict__ Qdn, const u16* __restrict__ Kdn,
    const u16* __restrict__ VT,  const u16* __restrict__ XqT,
    u16* __restrict__ And) {
  __shared__ __align__(16) u16 L[26880];   // 53760B: Kr 3x4096 | Vr 3x4096 | Ps 64x36
  u16* Kr = L;
  u16* Vr = L + 12288;
  u16* Ps = L + 24576;                     // stride 36 u16 per row

  const int tid = threadIdx.x;
  const int lane = tid & 63, w = tid >> 6;
  const int r = lane & 15, g = lane >> 4;
  const int dq = w >> 1, eh = w & 1;       // QK: wave = (16 d-rows) x (16 e-cols)
  const int nq = w >> 1, dh = w & 1;       // PV: wave = (32 npos/slice) x (32 d-cols)
  const int bid = blockIdx.x;
  const int dt = bid >> 7, hb = bid & 127; // 8 d-tiles of one (b,h) share bid%8 (XCD)
  const int h = hb & 7, b = hb >> 3;
  const int d0 = dt * 64, hn0 = h * NHD;

  const u16* Qg = Qdn + ((size_t)b * DD + d0) * NN + hn0;
  const u16* Kg = Kdn + ((size_t)b * DD) * NN + hn0;
  const u16* Vg = VT + ((size_t)b * NN + hn0) * DD;

  auto stage_k = [&](int s) {              // K[(s>>1)*32 +32e][(s&1)*128 +128n] -> Kr[s%3]
    const int e0 = (s >> 1) * 32, n0 = (s & 1) * 128;
    u16* dst = Kr + (s % 3) * 4096;
    int row = tid >> 4, u = tid & 15;      // 512 slots of 16B; 16 chunks/row
    gload_lds16(Kg + (size_t)(e0 + row) * NN + n0 + ((u ^ (row & 7)) * 8), dst + tid * 8);
  };
  auto stage_v = [&](int t) {              // V slice t: rows {x*64+(t&1)*32+i} x 32e -> Vr[t%3]
    const int e0 = (t >> 1) * 32, j = t & 1;
    u16* dst = Vr + (t % 3) * 4096;
    int rl = tid >> 2, u = tid & 3;        // 512 slots; 4 chunks/row (64B rows)
    int gn = (rl >> 5) * 64 + j * 32 + (rl & 31);
    gload_lds16(Vg + (size_t)gn * DD + e0 + ((u ^ (rl & 3)) * 8), dst + tid * 8);
  };

  // ---- prologue: Q[64][256] staged through Kr/Vr region -> qf regs, then K0,V0,K1
#pragma unroll
  for (int jj = 0; jj < 4; ++jj) {
    int s = jj * 512 + tid;                // 2048 slots; 32 chunks/row (512B rows)
    int row = s >> 5, u = s & 31;
    gload_lds16(Qg + (size_t)row * NN + ((u ^ (row & 7)) * 8), L + s * 8);
  }
  WAITCNT("vmcnt(0)");
  barrier_raw();
  s16x8 qf[8];                             // 32 VGPR: wave's 16 d-rows x 256 n
  {
    const int qrow = dq * 16 + r;
#pragma unroll
    for (int k2 = 0; k2 < 8; ++k2)
      qf[k2] = *(const s16x8*)&L[qrow * 256 + (((k2 * 4 + g) ^ (qrow & 7)) * 8)];
  }
  WAITCNT("lgkmcnt(0)");
  barrier_raw();                           // Q region free; issues below can't race
  stage_k(0); stage_v(0); stage_k(1);      // outstanding: [K0 V0 K1]

  float psum[4] = {};
  f32x4 acc_o[2][2][2] = {};               // [slice j][ms][nf-d]

  for (int et = 0; et < 16; ++et) {
    f32x4 acc_s = {};
    // ---- QK^T: 2 substeps over n (128 each)
#pragma unroll
    for (int cn = 0; cn < 2; ++cn) {
      const int s = et * 2 + cn;
      if (cn == 0)      WAITCNT("vmcnt(2)");   // K(s) landed (ledger)
      else if (et < 15) WAITCNT("vmcnt(2)");
      else              WAITCNT("vmcnt(1)");
      barrier_raw();                       // K chunk ready; all prev reads drained
      // stage AFTER the barrier: no W-A-R race with other waves' reads
      if (s + 1 < 32) stage_v(s + 1);
      if (s + 2 < 32) stage_k(s + 2);
      const u16* kb = Kr + (s % 3) * 4096;
      const int rowe = eh * 16 + r;
      __builtin_amdgcn_s_setprio(1);
#pragma unroll
      for (int kq = 0; kq < 4; ++kq) {
        s16x8 bv = *(const s16x8*)&kb[rowe * 128 + (((kq * 4 + g) ^ (rowe & 7)) * 8)];
        acc_s = mfma_bf16(qf[cn * 4 + kq], bv, acc_s);
      }
      __builtin_amdgcn_s_setprio(0);
      WAITCNT("lgkmcnt(0)");               // K reads drained (license next writes)
    }
    // ---- exp -> Ps (stride 36 u16: zero write conflicts), rowsum partials in regs
#pragma unroll
    for (int j = 0; j < 4; ++j) {
      int rowd = dq * 16 + g * 4 + j;
      int cole = eh * 16 + r;
      float p = __expf(acc_s[j] * 0.0625f);   // scale 1/sqrt(Nh)=1/16
      psum[j] += p;
      Ps[rowd * 36 + cole] = f2bf(p);
    }
    WAITCNT("lgkmcnt(0)");                 // Ps writes drained
    if (et < 15) WAITCNT("vmcnt(3)");      // V(2et),V(2et+1) landed
    else         WAITCNT("vmcnt(0)");
    barrier_raw();                         // Ps + both V slices ready
    // ---- PV: 2 slice phases
#pragma unroll
    for (int j = 0; j < 2; ++j) {
      const u16* vb = Vr + ((et * 2 + j) % 3) * 4096;
      s16x8 pb[2];
#pragma unroll
      for (int nf = 0; nf < 2; ++nf) {
        int rowd = dh * 32 + nf * 16 + r;
        s16x4 plo = *(const s16x4*)&Ps[rowd * 36 + g * 8];      // 8B-aligned halves
        s16x4 phi = *(const s16x4*)&Ps[rowd * 36 + g * 8 + 4];
        pb[nf] = __builtin_shufflevector(plo, phi, 0, 1, 2, 3, 4, 5, 6, 7);
      }
      __builtin_amdgcn_s_setprio(1);
#pragma unroll
      for (int ms = 0; ms < 2; ++ms) {
        int rl = nq * 32 + ms * 16 + r;
        s16x8 av = *(const s16x8*)((const char*)vb + rl * 64 + ((g * 16) ^ ((rl & 3) << 4)));
        acc_o[j][ms][0] = mfma_bf16(av, pb[0], acc_o[j][ms][0]);
        acc_o[j][ms][1] = mfma_bf16(av, pb[1], acc_o[j][ms][1]);
      }
      __builtin_amdgcn_s_setprio(0);
    }
    WAITCNT("lgkmcnt(0)");
    barrier_raw();                         // PV reads drained before next-et issues
  }

  // ---- rowsum reduce (deterministic; overlays dead Kr region)
  float* rs = (float*)L;                   // [8][16] partials, then [64] inv at +128
#pragma unroll
  for (int j = 0; j < 4; ++j) {
    float v = psum[j];
    v += __shfl_xor(v, 1);
    v += __shfl_xor(v, 2);
    v += __shfl_xor(v, 4);
    v += __shfl_xor(v, 8);
    if (r == 0) rs[w * 16 + g * 4 + j] = v;
  }
  __syncthreads();
  if (tid < 64) {
    int dqi = tid >> 4, i = tid & 15;
    rs[128 + tid] = 1.0f / (rs[(dqi * 2) * 16 + i] + rs[(dqi * 2 + 1) * 16 + i]);
  }
  __syncthreads();

  const u16* Xg = XqT + ((size_t)b * NN + hn0) * DD + d0;
  u16* Ag = And + ((size_t)b * NN + hn0) * DD + d0;
#pragma unroll
  for (int j = 0; j < 2; ++j)
#pragma unroll
    for (int ms = 0; ms < 2; ++ms)
#pragma unroll
      for (int nf = 0; nf < 2; ++nf) {
        const int dc = dh * 32 + nf * 16 + r;
        const float inv = rs[128 + dc];
#pragma unroll
        for (int jj = 0; jj < 4; ++jj) {
          const int npos = nq * 64 + j * 32 + ms * 16 + g * 4 + jj;
          float o = acc_o[j][ms][nf][jj] * inv;
          float xq = bf2f(Xg[(size_t)npos * DD + dc]);
          Ag[(size_t)npos * DD + dc] = f2bf(xq - o);
        }
      }
}

// ----------------------------------------------------------------
extern "C" void kernel_launch(void* const* d_in, const int* in_sizes, int n_in,
                              void* d_out, int out_size, void* d_ws, size_t ws_size,
                              hipStream_t stream) {
  const float* Xq = (const float*)d_in[0];
  const float* Xk = (const float*)d_in[1];
  const float* Xv = (const float*)d_in[2];
  const float* Wq = (const float*)d_in[3];
  const float* Wk = (const float*)d_in[4];
  const float* Wv = (const float*)d_in[5];
  const float* Wo = (const float*)d_in[6];
  float* out = (float*)d_out;

  char* ws = (char*)d_ws;
  const size_t MB = 1024 * 1024;
  // ws (130 MB): Wb [0,2) | XqT [2,34) | XvT->And [34,66) | Qdn [66,98) | XkT [98,130)
  // d_out (64+ MB): VTb [0,32) + Kdn [32,64) as scratch, overwritten by final GEMM.
  u16* Wb  = (u16*)ws;
  u16* XqT = (u16*)(ws + 2 * MB);
  u16* XvT = (u16*)(ws + 34 * MB);
  u16* And = XvT;                                 // XvT dead after V-GEMM
  u16* Qdn = (u16*)(ws + 66 * MB);
  u16* XkT = (u16*)(ws + 98 * MB);
  u16* VTb = (u16*)d_out;
  u16* Kdn = (u16*)d_out + (size_t)BB * NN * DD;

  k_cvt_w<<<dim3(256, 4), 256, 0, stream>>>(Wq, Wk, Wv, Wo, Wb);

  // all three transposes in one launch (z = which*16 + b)
  k_transpose3<<<dim3(NN / 64, DD / 64, BB * 3), 256, 0, stream>>>(
      Xq, Xk, Xv, XqT, XkT, XvT);

  // VT[b][n][o] = sum_i XvT[b][n][i] * Wv[o][i]
  k_gemm_nt<u16><<<dim3(NN / 128, DD / 128, BB), 256, 0, stream>>>(
      XvT, (long long)NN * DD, DD,
      Wb + 2 * DD * DD, 0, DD,
      VTb, (long long)NN * DD, DD, DD);
  // Qdn[b][o][n]
  k_gemm_nt<u16><<<dim3(DD / 128, NN / 128, BB), 256, 0, stream>>>(
      Wb, 0, DD,
      XqT, (long long)NN * DD, DD,
      Qdn, (long long)DD * NN, NN, DD);
  // Kdn[b][o][n]
  k_gemm_nt<u16><<<dim3(DD / 128, NN / 128, BB), 256, 0, stream>>>(
      Wb + 1 * DD * DD, 0, DD,
      XkT, (long long)NN * DD, DD,
      Kdn, (long long)DD * NN, NN, DD);

  // fused scores/softmax/PV/residual -> And (overlays dead XvT)
  k_attn_fused<<<dim3(1024), 512, 0, stream>>>(Qdn, Kdn, VTb, XqT, And);

  // out[b][o][n] = sum_i Wo[o][i] * And[b][n][i]  (fp32; overwrites VTb/Kdn scratch)
  k_gemm_nt<float><<<dim3(DD / 128, NN / 128, BB), 256, 0, stream>>>(
      Wb + 3 * DD * DD, 0, DD,
      And, (long long)NN * DD, DD,
      out, (long long)DD * NN, NN, DD);
}